// Round 19
// baseline (1216.809 us; speedup 1.0000x reference)
//
#include <hip/hip_runtime.h>

typedef unsigned short ushort_t;
typedef __attribute__((ext_vector_type(8))) short s16x8;
typedef __attribute__((ext_vector_type(4))) float f32x4;

#define T_STEPS 128
#define BATCH   128
#define KIN     512
#define HDIM    2048
#define KTOT    2560    // KIN + HDIM
#define NPACK   8192    // 4*HDIM
#define NKT     40      // KTOT/64
#define OUTDIM  512
#define TSTEPB  655360  // BATCH*KTOT*2 bytes per t-slot

#define SBAR()   asm volatile("s_barrier" ::: "memory")
#define WAITV(n) asm volatile("s_waitcnt vmcnt(" #n ")" ::: "memory")

__device__ __forceinline__ ushort_t f2bf(float f){
  union{float f;unsigned u;} v; v.f=f;
  unsigned r = v.u + 0x7fffu + ((v.u>>16)&1u);
  return (ushort_t)(r>>16);
}
__device__ __forceinline__ float bf2f(ushort_t u){
  union{unsigned u;float f;} v; v.u = ((unsigned)u)<<16; return v.f;
}
__device__ __forceinline__ float sigmoidf_(float x){ return 1.f/(1.f+__expf(-x)); }
__device__ __forceinline__ float tanhf_(float x){ return 1.f-2.f/(__expf(2.f*x)+1.f); }
__device__ __forceinline__ f32x4 mfma16(s16x8 a, s16x8 b, f32x4 c){
  return __builtin_amdgcn_mfma_f32_16x16x32_bf16(a,b,c,0,0,0);
}
__device__ __forceinline__ void gload16(const void* g, void* l){
  __builtin_amdgcn_global_load_lds((const __attribute__((address_space(1))) void*)g,
                                   (__attribute__((address_space(3))) void*)l, 16, 0, 0);
}
__device__ __forceinline__ void store_u32_sc(void* p, unsigned v){
  asm volatile("global_store_dword %0, %1, off sc0 sc1" :: "v"(p), "v"(v) : "memory");
}

// ---------------- pack kernels (unchanged) ----------------

__global__ __launch_bounds__(256) void pack_w(const float* __restrict__ Wx,
                                              const float* __restrict__ Wh,
                                              ushort_t* __restrict__ Wp){
  __shared__ ushort_t tile[64][72];
  int kT = blockIdx.x % NKT;
  int nT = blockIdx.x / NKT;
  int tx = threadIdx.x & 63;
  int ty = threadIdx.x >> 6;
  int s8 = 2*nT + (tx>>5);
  int g  = (tx>>3)&3;
  int j  = tx&7;
  int src_col = g*2048 + s8*8 + j;
  int k0 = kT*64;
  const float* W = (k0 < KIN) ? (Wx + (size_t)k0*NPACK)
                              : (Wh + (size_t)(k0-KIN)*NPACK);
  for (int kk = 0; kk < 64; kk += 4){
    int kl = kk + ty;
    tile[tx][kl] = f2bf(W[(size_t)kl*NPACK + src_col]);
  }
  __syncthreads();
  for (int rr = 0; rr < 64; rr += 4){
    int trow = rr + ty;
    Wp[(size_t)(nT*64 + trow)*KTOT + k0 + tx] = tile[trow][tx];
  }
}

__global__ __launch_bounds__(256) void pack_fcw(const float* __restrict__ fcw,
                                                ushort_t* __restrict__ fcwT){
  __shared__ ushort_t tile[64][72];
  int kT = blockIdx.x & 31;
  int nT = blockIdx.x >> 5;
  int tx = threadIdx.x & 63;
  int ty = threadIdx.x >> 6;
  int k0 = kT*64;
  int src_col = nT*64 + tx;
  for (int kk = 0; kk < 64; kk += 4){
    int kl = kk + ty;
    tile[tx][kl] = f2bf(fcw[(size_t)(k0+kl)*OUTDIM + src_col]);
  }
  __syncthreads();
  for (int rr = 0; rr < 64; rr += 4){
    int trow = rr + ty;
    fcwT[(size_t)(nT*64 + trow)*HDIM + k0 + tx] = tile[trow][tx];
  }
}

// prep: x->bf16 into xh x-region; h0=0 (write-through); combined bias; zero bar.
__global__ __launch_bounds__(256) void prep(const float* __restrict__ x,
                                            const float* __restrict__ bx,
                                            const float* __restrict__ bh,
                                            ushort_t* __restrict__ xh,
                                            float* __restrict__ bias,
                                            unsigned* __restrict__ bar){
  int idx = blockIdx.x*256 + threadIdx.x;          // 1,048,576 threads
  for (int i = idx; i < T_STEPS*BATCH*KIN; i += 1048576){
    int t = i / (BATCH*KIN);
    int r = (i / KIN) % BATCH;
    int k = i % KIN;
    xh[((size_t)t*BATCH + r)*KTOT + k] = f2bf(x[i]);
  }
  if (idx < BATCH*HDIM/2){
    int r = idx >> 10;
    int k2 = (idx & 1023)*2;
    store_u32_sc(xh + (size_t)r*KTOT + KIN + k2, 0u);
  }
  if (idx < NPACK){
    int s8 = idx>>5, g = (idx>>3)&3, j = idx&7;
    int sc = g*2048 + s8*8 + j;
    bias[idx] = bx[sc] + bh[sc];
  }
  if (idx < 1024) bar[idx] = 0u;
}

// ---------------- persistent LSTM v8: v7 + barrier hidden under x-phases ----
// grid 256 x 512 thr (8 waves = 2 nh x 4 ks). Tile 64r x 64c, K=2560 in 10
// phases of 256 k. Weights register-resident wfr[10][2][2] (160 regs, amp-2).
// NEW: the grid-barrier RELEASE POLL is moved to after phases 0,1 of the next
// step (k<512 = x-region, independent of h(t)): arrive is posted at end of
// step t (h-stores retired), block immediately computes the 2 x-phases while
// the release propagates; only h-region staging (phases 2..9) gates on the
// poll. Ring audit: phase2->buf2, phase3->buf0 staged after an unconditional
// syncthreads (all waves past phase1 -> buf0/1 reads consumed); the rest is
// the R15-proven single-barrier 3-buf argument. LDS 133,120 B.
__global__ __launch_bounds__(512)
void lstm_seq(const ushort_t* __restrict__ xh_c,
              ushort_t* __restrict__ xh,
              const ushort_t* __restrict__ Wp,
              const float* __restrict__ bias,
              float* __restrict__ cbuf,
              unsigned* __restrict__ bar){
  __shared__ alignas(16) ushort_t Abuf[3][16384];  // 3 x 32KB
  __shared__ alignas(16) float red[2][64][68];     // 34,816 B
  const int tid = threadIdx.x;
  const int l = tid & 63, w = tid >> 6;            // 8 waves
  const int lane16 = l & 15, q4 = l >> 4;
  const int nh = w & 1, ks = w >> 1;               // nh: col half, ks: 0..3
  const int bid = blockIdx.x;
  const int rt = ((bid & 7) >= 4) ? 1 : 0;
  const int cb = (bid & 3)*32 + (bid >> 3);

  // ---- weights: wfr[p][u][nf]; col=cb*64+nh*32+nf*16+lane16,
  //      k = p*256 + (2ks+u)*32 + q4*8
  s16x8 wfr[10][2][2];
  {
    const ushort_t* wp0 = Wp + (size_t)(cb*64 + nh*32 +      lane16)*KTOT + ks*64 + q4*8;
    const ushort_t* wp1 = Wp + (size_t)(cb*64 + nh*32 + 16 + lane16)*KTOT + ks*64 + q4*8;
#pragma unroll
    for (int p = 0; p < 10; ++p){
#pragma unroll
      for (int u = 0; u < 2; ++u){
        wfr[p][u][0] = *(const s16x8*)(wp0 + p*256 + u*32);
        wfr[p][u][1] = *(const s16x8*)(wp1 + p*256 + u*32);
      }
    }
  }

  // ---- staging: wave stages rows w*8..w*8+7; 4 gload16/thread/phase ----
  const int r0 = l >> 5;                   // 0/1
  const int u5 = l & 31;
  const char* base = (const char*)xh_c + (size_t)(rt*64 + w*8)*5120;
  const char* srcA0 = base + (size_t)(0 + r0)*5120 + ((u5 ^ ((0 + r0)&7))*16);
  const char* srcA1 = base + (size_t)(2 + r0)*5120 + ((u5 ^ ((2 + r0)&7))*16);
  const char* srcA2 = base + (size_t)(4 + r0)*5120 + ((u5 ^ ((4 + r0)&7))*16);
  const char* srcA3 = base + (size_t)(6 + r0)*5120 + ((u5 ^ ((6 + r0)&7))*16);
  char* ldsw = (char*)&Abuf[0][0] + w*4096;
  const char* ldsr = (const char*)&Abuf[0][0];

// B = buffer index 0..2; POFF = runtime byte offset on the ADDRESS
#define STG(B, POFF) do{ \
    gload16(srcA0 + (POFF), ldsw + (B)*32768); \
    gload16(srcA1 + (POFF), ldsw + (B)*32768 + 1024); \
    gload16(srcA2 + (POFF), ldsw + (B)*32768 + 2048); \
    gload16(srcA3 + (POFF), ldsw + (B)*32768 + 3072); }while(0)

  // ---- ds_read bases: row=mf*16+lane16; unit=((2ks+u)*4+q4) ^ (row&7) ----
  const int dsb0 = lane16*512 + ((((2*ks+0)*4 + q4) ^ (lane16 & 7)) << 4);
  const int dsb1 = lane16*512 + ((((2*ks+1)*4 + q4) ^ (lane16 & 7)) << 4);

  // ---- epilogue constants: 2 h-elems per thread (cols ehc, ehc+1) ----
  const int e0   = tid*2;
  const int erow = e0 >> 4;                // 0..63
  const int ehc  = e0 & 15;                // even
  const int cgb  = (ehc>>3)*32 + (ehc&7);  // local col of gate i (f:+8 o:+16 c:+24)
  const float2 bI = *(const float2*)(bias + cb*64 + cgb);
  const float2 bF = *(const float2*)(bias + cb*64 + cgb + 8);
  const float2 bO = *(const float2*)(bias + cb*64 + cgb + 16);
  const float2 bC = *(const float2*)(bias + cb*64 + cgb + 24);
  char* hptr = (char*)xh +
      ((size_t)(BATCH + rt*64 + erow)*KTOT + KIN + cb*16 + ehc)*2;
  float c0 = 0.f, c1 = 0.f;

  const int xcd = bid & 7;
  const int g4  = bid & 4;
  const bool is_root = (bid == g4);

// core of one phase (reads buf P%3; no STG)
#define PHASEBODY(P) do{ \
    const char* bp_ = ldsr + ((P)%3)*32768; \
    s16x8 a0_, a1_, a2_, a3_; \
    a0_ = *(const s16x8*)(bp_ + 0*8192 + dsb0); \
    a1_ = *(const s16x8*)(bp_ + 1*8192 + dsb0); \
    a2_ = *(const s16x8*)(bp_ + 2*8192 + dsb0); \
    a3_ = *(const s16x8*)(bp_ + 3*8192 + dsb0); \
    acc00 = mfma16(a0_, wfr[P][0][0], acc00); \
    acc10 = mfma16(a1_, wfr[P][0][0], acc10); \
    acc20 = mfma16(a2_, wfr[P][0][0], acc20); \
    acc30 = mfma16(a3_, wfr[P][0][0], acc30); \
    acc01 = mfma16(a0_, wfr[P][0][1], acc01); \
    acc11 = mfma16(a1_, wfr[P][0][1], acc11); \
    acc21 = mfma16(a2_, wfr[P][0][1], acc21); \
    acc31 = mfma16(a3_, wfr[P][0][1], acc31); \
    a0_ = *(const s16x8*)(bp_ + 0*8192 + dsb1); \
    a1_ = *(const s16x8*)(bp_ + 1*8192 + dsb1); \
    a2_ = *(const s16x8*)(bp_ + 2*8192 + dsb1); \
    a3_ = *(const s16x8*)(bp_ + 3*8192 + dsb1); \
    acc00 = mfma16(a0_, wfr[P][1][0], acc00); \
    acc10 = mfma16(a1_, wfr[P][1][0], acc10); \
    acc20 = mfma16(a2_, wfr[P][1][0], acc20); \
    acc30 = mfma16(a3_, wfr[P][1][0], acc30); \
    acc01 = mfma16(a0_, wfr[P][1][1], acc01); \
    acc11 = mfma16(a1_, wfr[P][1][1], acc11); \
    acc21 = mfma16(a2_, wfr[P][1][1], acc21); \
    acc31 = mfma16(a3_, wfr[P][1][1], acc31); \
  }while(0)

// x-phase: no STG (h-region staging is gated by the grid barrier)
#define PHASEX(P, WN) do{ WAITV(WN); SBAR(); PHASEBODY(P); }while(0)
// h-phase: stages phase P+2 into buf (P+2)%3 after compute (P=2..7)
#define PHASE(P, WN)  do{ WAITV(WN); SBAR(); PHASEBODY(P); \
    if ((P) < 8) STG((((P)+2)%3), ((P)+2)*512); }while(0)

  // prologue: stage t=0 phases 0,1 (x-region)
  STG(0, 0); STG(1, 512);

#pragma unroll 1
  for (int t = 0; t < T_STEPS; ++t){
    f32x4 acc00 = {0,0,0,0}, acc10 = {0,0,0,0}, acc20 = {0,0,0,0}, acc30 = {0,0,0,0};
    f32x4 acc01 = {0,0,0,0}, acc11 = {0,0,0,0}, acc21 = {0,0,0,0}, acc31 = {0,0,0,0};

    // ---- x-phases 0,1: independent of h(t); overlap the release poll ----
    PHASEX(0,4); PHASEX(1,0);

    // ---- release poll (arrive was posted at end of step t-1) ----
    if (t > 0 && tid == 0){
      unsigned tgt = (unsigned)t;
      if (is_root){
#pragma unroll 1
        for (int x2 = 0; x2 < 4; ++x2){
          unsigned* a2 = bar + (g4 + x2)*32;
          while (__hip_atomic_load(a2, __ATOMIC_RELAXED,
                                   __HIP_MEMORY_SCOPE_AGENT) < tgt*32u)
            __builtin_amdgcn_s_sleep(1);
        }
#pragma unroll 1
        for (int x2 = 0; x2 < 4; ++x2)
          __hip_atomic_store(bar + 256 + (g4 + x2)*32, tgt,
                             __ATOMIC_RELAXED, __HIP_MEMORY_SCOPE_AGENT);
      } else {
        unsigned* relw = bar + 256 + xcd*32;
        while (__hip_atomic_load(relw, __ATOMIC_RELAXED,
                                 __HIP_MEMORY_SCOPE_AGENT) < tgt)
          __builtin_amdgcn_s_sleep(1);
      }
    }
    __syncthreads();     // release seen; all waves past phases 0,1

    // ---- h-region staging + phases 2..9 ----
    STG(2, 1024); STG(0, 1536);          // phase2->buf2, phase3->buf0
    PHASE(2,4); PHASE(3,4); PHASE(4,4); PHASE(5,4);
    PHASE(6,4); PHASE(7,4); PHASE(8,4); PHASE(9,0);

    // ---- 2-phase reduction: ks>=2 write red[ks&1]; ks<2 accumulate ----
    {
      float* rp0 = &red[ks & 1][nh*32 +      lane16][0];
      float* rp1 = &red[ks & 1][nh*32 + 16 + lane16][0];
      if (ks >= 2){
        *(f32x4*)(rp0 + 0*16 + q4*4) = acc00;
        *(f32x4*)(rp0 + 1*16 + q4*4) = acc10;
        *(f32x4*)(rp0 + 2*16 + q4*4) = acc20;
        *(f32x4*)(rp0 + 3*16 + q4*4) = acc30;
        *(f32x4*)(rp1 + 0*16 + q4*4) = acc01;
        *(f32x4*)(rp1 + 1*16 + q4*4) = acc11;
        *(f32x4*)(rp1 + 2*16 + q4*4) = acc21;
        *(f32x4*)(rp1 + 3*16 + q4*4) = acc31;
      }
      __syncthreads();
      if (ks < 2){
        f32x4 v_;
        v_ = *(const f32x4*)(rp0 + 0*16 + q4*4); v_ += acc00; *(f32x4*)(rp0 + 0*16 + q4*4) = v_;
        v_ = *(const f32x4*)(rp0 + 1*16 + q4*4); v_ += acc10; *(f32x4*)(rp0 + 1*16 + q4*4) = v_;
        v_ = *(const f32x4*)(rp0 + 2*16 + q4*4); v_ += acc20; *(f32x4*)(rp0 + 2*16 + q4*4) = v_;
        v_ = *(const f32x4*)(rp0 + 3*16 + q4*4); v_ += acc30; *(f32x4*)(rp0 + 3*16 + q4*4) = v_;
        v_ = *(const f32x4*)(rp1 + 0*16 + q4*4); v_ += acc01; *(f32x4*)(rp1 + 0*16 + q4*4) = v_;
        v_ = *(const f32x4*)(rp1 + 1*16 + q4*4); v_ += acc11; *(f32x4*)(rp1 + 1*16 + q4*4) = v_;
        v_ = *(const f32x4*)(rp1 + 2*16 + q4*4); v_ += acc21; *(f32x4*)(rp1 + 2*16 + q4*4) = v_;
        v_ = *(const f32x4*)(rp1 + 3*16 + q4*4); v_ += acc31; *(f32x4*)(rp1 + 3*16 + q4*4) = v_;
      }
      __syncthreads();
    }

    // ---- epilogue: sum 2 slices, gates x2, c (regs), h (packed u32) ----
    float gI0 = bI.x, gI1 = bI.y, gF0 = bF.x, gF1 = bF.y;
    float gO0 = bO.x, gO1 = bO.y, gC0 = bC.x, gC1 = bC.y;
#pragma unroll
    for (int s2 = 0; s2 < 2; ++s2){
      const float* rr = &red[s2][0][0];
      gI0 += rr[(cgb     )*68 + erow];  gI1 += rr[(cgb +  1)*68 + erow];
      gF0 += rr[(cgb +  8)*68 + erow];  gF1 += rr[(cgb +  9)*68 + erow];
      gO0 += rr[(cgb + 16)*68 + erow];  gO1 += rr[(cgb + 17)*68 + erow];
      gC0 += rr[(cgb + 24)*68 + erow];  gC1 += rr[(cgb + 25)*68 + erow];
    }
    c0 = sigmoidf_(gF0)*c0 + sigmoidf_(gI0)*tanhf_(gC0);
    c1 = sigmoidf_(gF1)*c1 + sigmoidf_(gI1)*tanhf_(gC1);
    float h0 = sigmoidf_(gO0)*tanhf_(c0);
    float h1 = sigmoidf_(gO1)*tanhf_(c1);
    unsigned hpack = ((unsigned)f2bf(h1) << 16) | (unsigned)f2bf(h0);
    store_u32_sc(hptr, hpack);
    if (t == T_STEPS-1){
      float2 cv; cv.x = c0; cv.y = c1;
      *(float2*)(cbuf + (size_t)(rt*64 + erow)*HDIM + cb*16 + ehc) = cv;
    } else {
      hptr  += TSTEPB;
      srcA0 += TSTEPB;
      srcA1 += TSTEPB;
      srcA2 += TSTEPB;
      srcA3 += TSTEPB;
      // stage t+1 x-phases 0,1; retire h-store; post arrive (poll deferred)
      STG(0, 0); STG(1, 512);
      WAITV(8);                 // h-store retired; 8 stage loads in flight
      __syncthreads();
      if (tid == 0)
        __hip_atomic_fetch_add(bar + xcd*32, 1u, __ATOMIC_RELAXED,
                               __HIP_MEMORY_SCOPE_AGENT);
    }
  }
#undef PHASE
#undef PHASEX
#undef PHASEBODY
#undef STG
}

// ---------------- output GEMM (unchanged) ----------------
__global__ __launch_bounds__(256) void out_gemm(const ushort_t* __restrict__ A,
                                                const ushort_t* __restrict__ Bt,
                                                const float* __restrict__ fcb,
                                                float* __restrict__ out){
  __shared__ alignas(16) ushort_t Alds[3][4096];
  __shared__ alignas(16) ushort_t Blds[3][4096];
  const int tid = threadIdx.x;
  const int l = tid & 63, w = tid >> 6;
  const int b = blockIdx.x;
  const int orig = (b & 7)*256 + (b >> 3);
  const int rowt = orig >> 3;
  const int colt = orig & 7;
  const int sc = (l&7) ^ (l>>3);
  const int q4 = l>>4, d = l&7;
  const int swz0 = (q4 ^ d) << 4;
  const int swz1 = ((4+q4) ^ d) << 4;
  const int mrow0 = ((w>>1)*32) + (l&15);
  const int nrow0 = ((w&1)*32) + (l&15);
  f32x4 acc[2][2] = {};

  auto stage = [&](int kt, int buf){
    int k0 = kt*64;
#pragma unroll
    for (int q = 0; q < 2; ++q){
      int rowl = q*32 + w*8 + (l>>3);
      gload16(A  + (size_t)(rowt*64 + rowl)*KTOT + k0 + sc*8, &Alds[buf][(q*32+w*8)*64]);
      gload16(Bt + (size_t)(colt*64 + rowl)*HDIM + k0 + sc*8, &Blds[buf][(q*32+w*8)*64]);
    }
  };

  stage(0, 0); stage(1, 1); stage(2, 2);
  int buf = 0;
  for (int kt = 0; kt < 32; ++kt){
    if (kt < 30)       { WAITV(8); }
    else if (kt == 30) { WAITV(4); }
    else               { WAITV(0); }
    SBAR();
    const char* pa = (const char*)Alds[buf];
    const char* pb = (const char*)Blds[buf];
#pragma unroll
    for (int s = 0; s < 2; ++s){
      int swz = s ? swz1 : swz0;
      s16x8 a0 = *(const s16x8*)(pa + mrow0*128 + swz);
      s16x8 a1 = *(const s16x8*)(pa + (mrow0+16)*128 + swz);
      s16x8 b0 = *(const s16x8*)(pb + nrow0*128 + swz);
      s16x8 b1 = *(const s16x8*)(pb + (nrow0+16)*128 + swz);
      acc[0][0] = mfma16(a0, b0, acc[0][0]);
      acc[0][1] = mfma16(a0, b1, acc[0][1]);
      acc[1][0] = mfma16(a1, b0, acc[1][0]);
      acc[1][1] = mfma16(a1, b1, acc[1][1]);
    }
    SBAR();
    if (kt+3 < 32) stage(kt+3, buf);
    buf = (buf==2) ? 0 : buf+1;
  }
#pragma unroll
  for (int m = 0; m < 2; ++m){
#pragma unroll
    for (int f = 0; f < 2; ++f){
      int col = colt*64 + (w&1)*32 + f*16 + (l&15);
      float bb = fcb[col];
#pragma unroll
      for (int r = 0; r < 4; ++r){
        int row = rowt*64 + (w>>1)*32 + m*16 + q4*4 + r;
        out[(size_t)row*OUTDIM + col] = acc[m][f][r] + bb;
      }
    }
  }
}

// final h (bf16->f32) into d_out; c written by lstm_seq directly
__global__ __launch_bounds__(256) void finalize(const ushort_t* __restrict__ xh,
                                                float* __restrict__ out){
  int i = blockIdx.x*256 + threadIdx.x;
  for (; i < BATCH*HDIM; i += 131072){
    int r = i >> 11, k = i & 2047;
    out[(size_t)T_STEPS*BATCH*OUTDIM + i] =
        bf2f(xh[((size_t)T_STEPS*BATCH + r)*KTOT + KIN + k]);
  }
}

extern "C" void kernel_launch(void* const* d_in, const int* in_sizes, int n_in,
                              void* d_out, int out_size, void* d_ws, size_t ws_size,
                              hipStream_t stream){
  const float* x   = (const float*)d_in[0];
  const float* Wx  = (const float*)d_in[1];
  const float* Wh  = (const float*)d_in[2];
  const float* bx  = (const float*)d_in[3];
  const float* bh  = (const float*)d_in[4];
  const float* fcw = (const float*)d_in[5];
  const float* fcb = (const float*)d_in[6];
  float* out = (float*)d_out;
  char* ws = (char*)d_ws;

  ushort_t* Wp   = (ushort_t*)(ws + 0);              // 41,943,040
  ushort_t* fcwT = (ushort_t*)(ws + 41943040);       //  2,097,152
  ushort_t* xh   = (ushort_t*)(ws + 44040192);       // 84,541,440 (129 slots)
  float*    bias = (float*)   (ws + 128581632);      //     32,768
  unsigned* bar  = (unsigned*)(ws + 128614400);      //      4,096
  if (ws_size < (size_t)128618496) return;

  // c state written directly into its output slot: out + T*B*O + B*H
  float* cbuf = out + (size_t)T_STEPS*BATCH*OUTDIM + (size_t)BATCH*HDIM;

  pack_w  <<<NKT*128, 256, 0, stream>>>(Wx, Wh, Wp);
  pack_fcw<<<32*8,    256, 0, stream>>>(fcw, fcwT);
  prep    <<<4096,    256, 0, stream>>>(x, bx, bh, xh, bias, bar);
  lstm_seq<<<256, 512, 0, stream>>>(xh, xh, Wp, bias, cbuf, bar);
  out_gemm<<<2048, 256, 0, stream>>>(xh + (size_t)BATCH*KTOT + KIN, fcwT, fcb, out);
  finalize<<<512, 256, 0, stream>>>(xh, out);
}

// Round 20
// 1160.532 us; speedup vs baseline: 1.0485x; 1.0485x over previous
//
#include <hip/hip_runtime.h>

typedef unsigned short ushort_t;
typedef __attribute__((ext_vector_type(8))) short s16x8;
typedef __attribute__((ext_vector_type(4))) float f32x4;

#define T_STEPS 128
#define BATCH   128
#define KIN     512
#define HDIM    2048
#define KTOT    2560    // KIN + HDIM
#define NPACK   8192    // 4*HDIM
#define NKT     40      // KTOT/64
#define OUTDIM  512
#define TSTEPB  655360  // BATCH*KTOT*2 bytes per t-slot

#define SBAR()   asm volatile("s_barrier" ::: "memory")
#define WAITV(n) asm volatile("s_waitcnt vmcnt(" #n ")" ::: "memory")

__device__ __forceinline__ ushort_t f2bf(float f){
  union{float f;unsigned u;} v; v.f=f;
  unsigned r = v.u + 0x7fffu + ((v.u>>16)&1u);
  return (ushort_t)(r>>16);
}
__device__ __forceinline__ float bf2f(ushort_t u){
  union{unsigned u;float f;} v; v.u = ((unsigned)u)<<16; return v.f;
}
__device__ __forceinline__ float sigmoidf_(float x){ return 1.f/(1.f+__expf(-x)); }
__device__ __forceinline__ float tanhf_(float x){ return 1.f-2.f/(__expf(2.f*x)+1.f); }
__device__ __forceinline__ f32x4 mfma16(s16x8 a, s16x8 b, f32x4 c){
  return __builtin_amdgcn_mfma_f32_16x16x32_bf16(a,b,c,0,0,0);
}
__device__ __forceinline__ void gload16(const void* g, void* l){
  __builtin_amdgcn_global_load_lds((const __attribute__((address_space(1))) void*)g,
                                   (__attribute__((address_space(3))) void*)l, 16, 0, 0);
}
__device__ __forceinline__ void store_u32_sc(void* p, unsigned v){
  asm volatile("global_store_dword %0, %1, off sc0 sc1" :: "v"(p), "v"(v) : "memory");
}

// ---------------- pack kernels ----------------

__global__ __launch_bounds__(256) void pack_w(const float* __restrict__ Wx,
                                              const float* __restrict__ Wh,
                                              ushort_t* __restrict__ Wp){
  __shared__ ushort_t tile[64][72];
  int kT = blockIdx.x % NKT;
  int nT = blockIdx.x / NKT;
  int tx = threadIdx.x & 63;
  int ty = threadIdx.x >> 6;
  int s8 = 2*nT + (tx>>5);
  int g  = (tx>>3)&3;
  int j  = tx&7;
  int src_col = g*2048 + s8*8 + j;
  int k0 = kT*64;
  const float* W = (k0 < KIN) ? (Wx + (size_t)k0*NPACK)
                              : (Wh + (size_t)(k0-KIN)*NPACK);
  for (int kk = 0; kk < 64; kk += 4){
    int kl = kk + ty;
    tile[tx][kl] = f2bf(W[(size_t)kl*NPACK + src_col]);
  }
  __syncthreads();
  for (int rr = 0; rr < 64; rr += 4){
    int trow = rr + ty;
    Wp[(size_t)(nT*64 + trow)*KTOT + k0 + tx] = tile[trow][tx];
  }
}

__global__ __launch_bounds__(256) void pack_fcw(const float* __restrict__ fcw,
                                                ushort_t* __restrict__ fcwT){
  __shared__ ushort_t tile[64][72];
  int kT = blockIdx.x & 31;
  int nT = blockIdx.x >> 5;
  int tx = threadIdx.x & 63;
  int ty = threadIdx.x >> 6;
  int k0 = kT*64;
  int src_col = nT*64 + tx;
  for (int kk = 0; kk < 64; kk += 4){
    int kl = kk + ty;
    tile[tx][kl] = f2bf(fcw[(size_t)(k0+kl)*OUTDIM + src_col]);
  }
  __syncthreads();
  for (int rr = 0; rr < 64; rr += 4){
    int trow = rr + ty;
    fcwT[(size_t)(nT*64 + trow)*HDIM + k0 + tx] = tile[trow][tx];
  }
}

// prep: x->bf16 into xh x-region; h0=0 (write-through); combined bias; zero bar.
__global__ __launch_bounds__(256) void prep(const float* __restrict__ x,
                                            const float* __restrict__ bx,
                                            const float* __restrict__ bh,
                                            ushort_t* __restrict__ xh,
                                            float* __restrict__ bias,
                                            unsigned* __restrict__ bar){
  int idx = blockIdx.x*256 + threadIdx.x;          // 1,048,576 threads
  for (int i = idx; i < T_STEPS*BATCH*KIN; i += 1048576){
    int t = i / (BATCH*KIN);
    int r = (i / KIN) % BATCH;
    int k = i % KIN;
    xh[((size_t)t*BATCH + r)*KTOT + k] = f2bf(x[i]);
  }
  if (idx < BATCH*HDIM/2){
    int r = idx >> 10;
    int k2 = (idx & 1023)*2;
    store_u32_sc(xh + (size_t)r*KTOT + KIN + k2, 0u);
  }
  if (idx < NPACK){
    int s8 = idx>>5, g = (idx>>3)&3, j = idx&7;
    int sc = g*2048 + s8*8 + j;
    bias[idx] = bx[sc] + bh[sc];
  }
  if (idx < 1024) bar[idx] = 0u;
}

// ---------------- persistent LSTM v7 (R18 best): 8 waves, amp-2, 160reg -----
// grid 256 x 512 thr (8 waves = 2 nh x 4 ks, 2 waves/SIMD). Tile 64r x 64c,
// K=2560 in 10 phases of 256 k. Wave (nh,ks): cols nh*32..+32, k-class ks
// owns kf = 8p + 2ks + u (u=0,1) -> 640 k. Weights fully register-resident:
// wfr[10][2][2] = 160 regs/lane (amp-2 midpoint of the A-dup/weight-dup
// duality). A staged per phase (32KB) into THREE LDS bufs via global_load_lds
// — single s_barrier/phase 3-buf ring (R15-verified safety), counted WAITV(4).
// Per CU per phase: 64 ds_read_b128 + 128 MFMA. 4 k-partials -> 2-phase
// red[2] reduction. LDS 133,120 B. 1167 us verified (R18).
__global__ __launch_bounds__(512)
void lstm_seq(const ushort_t* __restrict__ xh_c,
              ushort_t* __restrict__ xh,
              const ushort_t* __restrict__ Wp,
              const float* __restrict__ bias,
              float* __restrict__ cbuf,
              unsigned* __restrict__ bar){
  __shared__ alignas(16) ushort_t Abuf[3][16384];  // 3 x 32KB
  __shared__ alignas(16) float red[2][64][68];     // 34,816 B
  const int tid = threadIdx.x;
  const int l = tid & 63, w = tid >> 6;            // 8 waves
  const int lane16 = l & 15, q4 = l >> 4;
  const int nh = w & 1, ks = w >> 1;               // nh: col half, ks: 0..3
  const int bid = blockIdx.x;
  const int rt = ((bid & 7) >= 4) ? 1 : 0;
  const int cb = (bid & 3)*32 + (bid >> 3);

  // ---- weights: wfr[p][u][nf]; col=cb*64+nh*32+nf*16+lane16,
  //      k = p*256 + (2ks+u)*32 + q4*8
  s16x8 wfr[10][2][2];
  {
    const ushort_t* wp0 = Wp + (size_t)(cb*64 + nh*32 +      lane16)*KTOT + ks*64 + q4*8;
    const ushort_t* wp1 = Wp + (size_t)(cb*64 + nh*32 + 16 + lane16)*KTOT + ks*64 + q4*8;
#pragma unroll
    for (int p = 0; p < 10; ++p){
#pragma unroll
      for (int u = 0; u < 2; ++u){
        wfr[p][u][0] = *(const s16x8*)(wp0 + p*256 + u*32);
        wfr[p][u][1] = *(const s16x8*)(wp1 + p*256 + u*32);
      }
    }
  }

  // ---- staging: wave stages rows w*8..w*8+7; 4 gload16/thread/phase ----
  const int r0 = l >> 5;                   // 0/1
  const int u5 = l & 31;
  const char* base = (const char*)xh_c + (size_t)(rt*64 + w*8)*5120;
  const char* srcA0 = base + (size_t)(0 + r0)*5120 + ((u5 ^ ((0 + r0)&7))*16);
  const char* srcA1 = base + (size_t)(2 + r0)*5120 + ((u5 ^ ((2 + r0)&7))*16);
  const char* srcA2 = base + (size_t)(4 + r0)*5120 + ((u5 ^ ((4 + r0)&7))*16);
  const char* srcA3 = base + (size_t)(6 + r0)*5120 + ((u5 ^ ((6 + r0)&7))*16);
  char* ldsw = (char*)&Abuf[0][0] + w*4096;
  const char* ldsr = (const char*)&Abuf[0][0];

// B = buffer index 0..2; POFF = runtime byte offset on the ADDRESS
#define STG(B, POFF) do{ \
    gload16(srcA0 + (POFF), ldsw + (B)*32768); \
    gload16(srcA1 + (POFF), ldsw + (B)*32768 + 1024); \
    gload16(srcA2 + (POFF), ldsw + (B)*32768 + 2048); \
    gload16(srcA3 + (POFF), ldsw + (B)*32768 + 3072); }while(0)

  // ---- ds_read bases: row=mf*16+lane16; unit=((2ks+u)*4+q4) ^ (row&7) ----
  const int dsb0 = lane16*512 + ((((2*ks+0)*4 + q4) ^ (lane16 & 7)) << 4);
  const int dsb1 = lane16*512 + ((((2*ks+1)*4 + q4) ^ (lane16 & 7)) << 4);

  // ---- epilogue constants: 2 h-elems per thread (cols ehc, ehc+1) ----
  const int e0   = tid*2;
  const int erow = e0 >> 4;                // 0..63
  const int ehc  = e0 & 15;                // even
  const int cgb  = (ehc>>3)*32 + (ehc&7);  // local col of gate i (f:+8 o:+16 c:+24)
  const float2 bI = *(const float2*)(bias + cb*64 + cgb);
  const float2 bF = *(const float2*)(bias + cb*64 + cgb + 8);
  const float2 bO = *(const float2*)(bias + cb*64 + cgb + 16);
  const float2 bC = *(const float2*)(bias + cb*64 + cgb + 24);
  char* hptr = (char*)xh +
      ((size_t)(BATCH + rt*64 + erow)*KTOT + KIN + cb*16 + ehc)*2;
  float c0 = 0.f, c1 = 0.f;

  const int xcd = bid & 7;
  const int g4  = bid & 4;
  const bool is_root = (bid == g4);

// one barrier per phase; read buf P%3; stage phase P+2 into buf (P+2)%3
#define PHASE(P, WN) do{ \
    WAITV(WN); SBAR(); \
    const char* bp_ = ldsr + ((P)%3)*32768; \
    s16x8 a0_, a1_, a2_, a3_; \
    a0_ = *(const s16x8*)(bp_ + 0*8192 + dsb0); \
    a1_ = *(const s16x8*)(bp_ + 1*8192 + dsb0); \
    a2_ = *(const s16x8*)(bp_ + 2*8192 + dsb0); \
    a3_ = *(const s16x8*)(bp_ + 3*8192 + dsb0); \
    acc00 = mfma16(a0_, wfr[P][0][0], acc00); \
    acc10 = mfma16(a1_, wfr[P][0][0], acc10); \
    acc20 = mfma16(a2_, wfr[P][0][0], acc20); \
    acc30 = mfma16(a3_, wfr[P][0][0], acc30); \
    acc01 = mfma16(a0_, wfr[P][0][1], acc01); \
    acc11 = mfma16(a1_, wfr[P][0][1], acc11); \
    acc21 = mfma16(a2_, wfr[P][0][1], acc21); \
    acc31 = mfma16(a3_, wfr[P][0][1], acc31); \
    a0_ = *(const s16x8*)(bp_ + 0*8192 + dsb1); \
    a1_ = *(const s16x8*)(bp_ + 1*8192 + dsb1); \
    a2_ = *(const s16x8*)(bp_ + 2*8192 + dsb1); \
    a3_ = *(const s16x8*)(bp_ + 3*8192 + dsb1); \
    acc00 = mfma16(a0_, wfr[P][1][0], acc00); \
    acc10 = mfma16(a1_, wfr[P][1][0], acc10); \
    acc20 = mfma16(a2_, wfr[P][1][0], acc20); \
    acc30 = mfma16(a3_, wfr[P][1][0], acc30); \
    acc01 = mfma16(a0_, wfr[P][1][1], acc01); \
    acc11 = mfma16(a1_, wfr[P][1][1], acc11); \
    acc21 = mfma16(a2_, wfr[P][1][1], acc21); \
    acc31 = mfma16(a3_, wfr[P][1][1], acc31); \
    if ((P) < 8) STG((((P)+2)%3), ((P)+2)*512); \
  }while(0)

  // prologue: stage t=0 phases 0,1 (x-region)
  STG(0, 0); STG(1, 512);

#pragma unroll 1
  for (int t = 0; t < T_STEPS; ++t){
    f32x4 acc00 = {0,0,0,0}, acc10 = {0,0,0,0}, acc20 = {0,0,0,0}, acc30 = {0,0,0,0};
    f32x4 acc01 = {0,0,0,0}, acc11 = {0,0,0,0}, acc21 = {0,0,0,0}, acc31 = {0,0,0,0};
    PHASE(0,4); PHASE(1,4); PHASE(2,4); PHASE(3,4); PHASE(4,4);
    PHASE(5,4); PHASE(6,4); PHASE(7,4); PHASE(8,4); PHASE(9,0);

    // ---- 2-phase reduction: ks>=2 write red[ks&1]; ks<2 accumulate ----
    {
      float* rp0 = &red[ks & 1][nh*32 +      lane16][0];
      float* rp1 = &red[ks & 1][nh*32 + 16 + lane16][0];
      if (ks >= 2){
        *(f32x4*)(rp0 + 0*16 + q4*4) = acc00;
        *(f32x4*)(rp0 + 1*16 + q4*4) = acc10;
        *(f32x4*)(rp0 + 2*16 + q4*4) = acc20;
        *(f32x4*)(rp0 + 3*16 + q4*4) = acc30;
        *(f32x4*)(rp1 + 0*16 + q4*4) = acc01;
        *(f32x4*)(rp1 + 1*16 + q4*4) = acc11;
        *(f32x4*)(rp1 + 2*16 + q4*4) = acc21;
        *(f32x4*)(rp1 + 3*16 + q4*4) = acc31;
      }
      __syncthreads();
      if (ks < 2){
        f32x4 v_;
        v_ = *(const f32x4*)(rp0 + 0*16 + q4*4); v_ += acc00; *(f32x4*)(rp0 + 0*16 + q4*4) = v_;
        v_ = *(const f32x4*)(rp0 + 1*16 + q4*4); v_ += acc10; *(f32x4*)(rp0 + 1*16 + q4*4) = v_;
        v_ = *(const f32x4*)(rp0 + 2*16 + q4*4); v_ += acc20; *(f32x4*)(rp0 + 2*16 + q4*4) = v_;
        v_ = *(const f32x4*)(rp0 + 3*16 + q4*4); v_ += acc30; *(f32x4*)(rp0 + 3*16 + q4*4) = v_;
        v_ = *(const f32x4*)(rp1 + 0*16 + q4*4); v_ += acc01; *(f32x4*)(rp1 + 0*16 + q4*4) = v_;
        v_ = *(const f32x4*)(rp1 + 1*16 + q4*4); v_ += acc11; *(f32x4*)(rp1 + 1*16 + q4*4) = v_;
        v_ = *(const f32x4*)(rp1 + 2*16 + q4*4); v_ += acc21; *(f32x4*)(rp1 + 2*16 + q4*4) = v_;
        v_ = *(const f32x4*)(rp1 + 3*16 + q4*4); v_ += acc31; *(f32x4*)(rp1 + 3*16 + q4*4) = v_;
      }
      __syncthreads();
    }

    // ---- epilogue: sum 2 slices, gates x2, c (regs), h (packed u32) ----
    float gI0 = bI.x, gI1 = bI.y, gF0 = bF.x, gF1 = bF.y;
    float gO0 = bO.x, gO1 = bO.y, gC0 = bC.x, gC1 = bC.y;
#pragma unroll
    for (int s2 = 0; s2 < 2; ++s2){
      const float* rr = &red[s2][0][0];
      gI0 += rr[(cgb     )*68 + erow];  gI1 += rr[(cgb +  1)*68 + erow];
      gF0 += rr[(cgb +  8)*68 + erow];  gF1 += rr[(cgb +  9)*68 + erow];
      gO0 += rr[(cgb + 16)*68 + erow];  gO1 += rr[(cgb + 17)*68 + erow];
      gC0 += rr[(cgb + 24)*68 + erow];  gC1 += rr[(cgb + 25)*68 + erow];
    }
    c0 = sigmoidf_(gF0)*c0 + sigmoidf_(gI0)*tanhf_(gC0);
    c1 = sigmoidf_(gF1)*c1 + sigmoidf_(gI1)*tanhf_(gC1);
    float h0 = sigmoidf_(gO0)*tanhf_(c0);
    float h1 = sigmoidf_(gO1)*tanhf_(c1);
    unsigned hpack = ((unsigned)f2bf(h1) << 16) | (unsigned)f2bf(h0);
    store_u32_sc(hptr, hpack);
    if (t == T_STEPS-1){
      float2 cv; cv.x = c0; cv.y = c1;
      *(float2*)(cbuf + (size_t)(rt*64 + erow)*HDIM + cb*16 + ehc) = cv;
    } else {
      hptr  += TSTEPB;
      srcA0 += TSTEPB;
      srcA1 += TSTEPB;
      srcA2 += TSTEPB;
      srcA3 += TSTEPB;
      // stage t+1 phases 0,1 (x-region, h-independent) before the barrier
      STG(0, 0); STG(1, 512);
      WAITV(8);                 // h-store retired; 8 stage loads in flight
      __syncthreads();
      if (tid == 0){
        __hip_atomic_fetch_add(bar + xcd*32, 1u, __ATOMIC_RELAXED,
                               __HIP_MEMORY_SCOPE_AGENT);
        unsigned tgt = (unsigned)(t+1);
        if (is_root){
#pragma unroll 1
          for (int x2 = 0; x2 < 4; ++x2){
            unsigned* a2 = bar + (g4 + x2)*32;
            while (__hip_atomic_load(a2, __ATOMIC_RELAXED,
                                     __HIP_MEMORY_SCOPE_AGENT) < tgt*32u)
              __builtin_amdgcn_s_sleep(1);
          }
#pragma unroll 1
          for (int x2 = 0; x2 < 4; ++x2)
            __hip_atomic_store(bar + 256 + (g4 + x2)*32, tgt,
                               __ATOMIC_RELAXED, __HIP_MEMORY_SCOPE_AGENT);
        } else {
          unsigned* relw = bar + 256 + xcd*32;
          while (__hip_atomic_load(relw, __ATOMIC_RELAXED,
                                   __HIP_MEMORY_SCOPE_AGENT) < tgt)
            __builtin_amdgcn_s_sleep(1);
        }
      }
      __syncthreads();
    }
  }
#undef PHASE
#undef STG
}

// ---------------- output GEMM ----------------
__global__ __launch_bounds__(256) void out_gemm(const ushort_t* __restrict__ A,
                                                const ushort_t* __restrict__ Bt,
                                                const float* __restrict__ fcb,
                                                float* __restrict__ out){
  __shared__ alignas(16) ushort_t Alds[3][4096];
  __shared__ alignas(16) ushort_t Blds[3][4096];
  const int tid = threadIdx.x;
  const int l = tid & 63, w = tid >> 6;
  const int b = blockIdx.x;
  const int orig = (b & 7)*256 + (b >> 3);
  const int rowt = orig >> 3;
  const int colt = orig & 7;
  const int sc = (l&7) ^ (l>>3);
  const int q4 = l>>4, d = l&7;
  const int swz0 = (q4 ^ d) << 4;
  const int swz1 = ((4+q4) ^ d) << 4;
  const int mrow0 = ((w>>1)*32) + (l&15);
  const int nrow0 = ((w&1)*32) + (l&15);
  f32x4 acc[2][2] = {};

  auto stage = [&](int kt, int buf){
    int k0 = kt*64;
#pragma unroll
    for (int q = 0; q < 2; ++q){
      int rowl = q*32 + w*8 + (l>>3);
      gload16(A  + (size_t)(rowt*64 + rowl)*KTOT + k0 + sc*8, &Alds[buf][(q*32+w*8)*64]);
      gload16(Bt + (size_t)(colt*64 + rowl)*HDIM + k0 + sc*8, &Blds[buf][(q*32+w*8)*64]);
    }
  };

  stage(0, 0); stage(1, 1); stage(2, 2);
  int buf = 0;
  for (int kt = 0; kt < 32; ++kt){
    if (kt < 30)       { WAITV(8); }
    else if (kt == 30) { WAITV(4); }
    else               { WAITV(0); }
    SBAR();
    const char* pa = (const char*)Alds[buf];
    const char* pb = (const char*)Blds[buf];
#pragma unroll
    for (int s = 0; s < 2; ++s){
      int swz = s ? swz1 : swz0;
      s16x8 a0 = *(const s16x8*)(pa + mrow0*128 + swz);
      s16x8 a1 = *(const s16x8*)(pa + (mrow0+16)*128 + swz);
      s16x8 b0 = *(const s16x8*)(pb + nrow0*128 + swz);
      s16x8 b1 = *(const s16x8*)(pb + (nrow0+16)*128 + swz);
      acc[0][0] = mfma16(a0, b0, acc[0][0]);
      acc[0][1] = mfma16(a0, b1, acc[0][1]);
      acc[1][0] = mfma16(a1, b0, acc[1][0]);
      acc[1][1] = mfma16(a1, b1, acc[1][1]);
    }
    SBAR();
    if (kt+3 < 32) stage(kt+3, buf);
    buf = (buf==2) ? 0 : buf+1;
  }
#pragma unroll
  for (int m = 0; m < 2; ++m){
#pragma unroll
    for (int f = 0; f < 2; ++f){
      int col = colt*64 + (w&1)*32 + f*16 + (l&15);
      float bb = fcb[col];
#pragma unroll
      for (int r = 0; r < 4; ++r){
        int row = rowt*64 + (w>>1)*32 + m*16 + q4*4 + r;
        out[(size_t)row*OUTDIM + col] = acc[m][f][r] + bb;
      }
    }
  }
}

// final h (bf16->f32) into d_out; c written by lstm_seq directly
__global__ __launch_bounds__(256) void finalize(const ushort_t* __restrict__ xh,
                                                float* __restrict__ out){
  int i = blockIdx.x*256 + threadIdx.x;
  for (; i < BATCH*HDIM; i += 131072){
    int r = i >> 11, k = i & 2047;
    out[(size_t)T_STEPS*BATCH*OUTDIM + i] =
        bf2f(xh[((size_t)T_STEPS*BATCH + r)*KTOT + KIN + k]);
  }
}

extern "C" void kernel_launch(void* const* d_in, const int* in_sizes, int n_in,
                              void* d_out, int out_size, void* d_ws, size_t ws_size,
                              hipStream_t stream){
  const float* x   = (const float*)d_in[0];
  const float* Wx  = (const float*)d_in[1];
  const float* Wh  = (const float*)d_in[2];
  const float* bx  = (const float*)d_in[3];
  const float* bh  = (const float*)d_in[4];
  const float* fcw = (const float*)d_in[5];
  const float* fcb = (const float*)d_in[6];
  float* out = (float*)d_out;
  char* ws = (char*)d_ws;

  ushort_t* Wp   = (ushort_t*)(ws + 0);              // 41,943,040
  ushort_t* fcwT = (ushort_t*)(ws + 41943040);       //  2,097,152
  ushort_t* xh   = (ushort_t*)(ws + 44040192);       // 84,541,440 (129 slots)
  float*    bias = (float*)   (ws + 128581632);      //     32,768
  unsigned* bar  = (unsigned*)(ws + 128614400);      //      4,096
  if (ws_size < (size_t)128618496) return;

  // c state written directly into its output slot: out + T*B*O + B*H
  float* cbuf = out + (size_t)T_STEPS*BATCH*OUTDIM + (size_t)BATCH*HDIM;

  pack_w  <<<NKT*128, 256, 0, stream>>>(Wx, Wh, Wp);
  pack_fcw<<<32*8,    256, 0, stream>>>(fcw, fcwT);
  prep    <<<4096,    256, 0, stream>>>(x, bx, bh, xh, bias, bar);
  lstm_seq<<<256, 512, 0, stream>>>(xh, xh, Wp, bias, cbuf, bar);
  out_gemm<<<2048, 256, 0, stream>>>(xh + (size_t)BATCH*KTOT + KIN, fcwT, fcb, out);
  finalize<<<512, 256, 0, stream>>>(xh, out);
}